// Round 13
// baseline (441.264 us; speedup 1.0000x reference)
//
#include <hip/hip_runtime.h>

#define NN 100000
#define NE 3200000
#define FIN 128
#define HID 32
#define MH  64
#define NC  10
#define NG  64
#define NBKT 782           // ceil(NN/128) buckets of 128 dest nodes
#define NBLK 512           // edge-pass blocks
#define EPB  (NE / NBLK)   // 6250 edges per block
#define SCANL (NBKT * NBLK)
#define SRCMASK 0x1FFFF    // src < 100000 < 2^17
#define BCAP 5120          // bucket LDS capacity (mean 4092, sd ~64)

typedef float floatx2 __attribute__((ext_vector_type(2)));

// per-block LDS histogram over 782 dest-buckets; no global atomics
__global__ __launch_bounds__(1024)
void hist_bkt(const int* __restrict__ ei, int* __restrict__ cnt2) {
    __shared__ int h[NBKT];
    int tid = threadIdx.x, blk = blockIdx.x;
    for (int b = tid; b < NBKT; b += 1024) h[b] = 0;
    __syncthreads();
    int base = blk * EPB;
    for (int i = tid; i < EPB; i += 1024)
        atomicAdd(&h[ei[NE + base + i] >> 7], 1);
    __syncthreads();
    for (int b = tid; b < NBKT; b += 1024) cnt2[b * NBLK + blk] = h[b];
}

// ---- generic exclusive scan (1024 elems/block) ----
__global__ void scan_block(const int* __restrict__ in, int* __restrict__ out,
                           int* __restrict__ bsum, int n) {
    __shared__ int lds[256];
    int tid = threadIdx.x;
    int base = blockIdx.x * 1024 + tid * 4;
    int v0 = 0, v1 = 0, v2 = 0, v3 = 0;
    if (base + 0 < n) v0 = in[base + 0];
    if (base + 1 < n) v1 = in[base + 1];
    if (base + 2 < n) v2 = in[base + 2];
    if (base + 3 < n) v3 = in[base + 3];
    int s = v0 + v1 + v2 + v3;
    lds[tid] = s;
    __syncthreads();
    for (int off = 1; off < 256; off <<= 1) {
        int val = (tid >= off) ? lds[tid - off] : 0;
        __syncthreads();
        lds[tid] += val;
        __syncthreads();
    }
    int excl = lds[tid] - s;
    if (tid == 255) bsum[blockIdx.x] = lds[255];
    if (base + 0 < n) out[base + 0] = excl;
    if (base + 1 < n) out[base + 1] = excl + v0;
    if (base + 2 < n) out[base + 2] = excl + v0 + v1;
    if (base + 3 < n) out[base + 3] = excl + v0 + v1 + v2;
}

// wave-parallel exclusive scan of bsum (chunked shuffle scan with carry)
__global__ void scan_top(int* __restrict__ bsum, int nb) {
    int lane = threadIdx.x;  // 64 threads
    int carry = 0;
    for (int base = 0; base < nb; base += 64) {
        int i = base + lane;
        int orig = (i < nb) ? bsum[i] : 0;
        int v = orig;
#pragma unroll
        for (int off = 1; off < 64; off <<= 1) {
            int t = __shfl_up(v, off, 64);
            if (lane >= off) v += t;
        }
        if (i < nb) bsum[i] = carry + v - orig;   // exclusive
        carry += __shfl(v, 63, 64);
    }
}

__global__ void scan_add(int* __restrict__ data, const int* __restrict__ bsum, int n) {
    int i = blockIdx.x * 256 + threadIdx.x;
    if (i < n) data[i] += bsum[i >> 10];
}

// single global read: pack each edge into LDS at its sorted slot, then
// slot-major burst writes to tre.
__global__ __launch_bounds__(1024)
void scatter_bkt(const int* __restrict__ ei, const float* __restrict__ ew,
                 const int* __restrict__ cnt2, const int* __restrict__ scanned,
                 int2* __restrict__ tre) {
    __shared__ int2 pay[EPB];      // 50 KB
    __shared__ int scur[NBKT];
    __shared__ int hexc[NBKT];
    __shared__ int gbase[NBKT];
    int tid = threadIdx.x, blk = blockIdx.x;
    int myh = 0;
    if (tid < NBKT) {
        myh = cnt2[tid * NBLK + blk];
        gbase[tid] = scanned[tid * NBLK + blk];
        scur[tid] = myh;
    }
    __syncthreads();
    for (int off = 1; off < NBKT; off <<= 1) {
        int v = (tid < NBKT && tid >= off) ? scur[tid - off] : 0;
        __syncthreads();
        if (tid < NBKT) scur[tid] += v;
        __syncthreads();
    }
    if (tid < NBKT) { int ex = scur[tid] - myh; hexc[tid] = ex; scur[tid] = ex; }
    __syncthreads();
    int base = blk * EPB;
    for (int i = tid; i < EPB; i += 1024) {
        int e = base + i;
        int c = ei[NE + e];
        int r = ei[e];
        unsigned int wb = __float_as_uint(ew[e]);
        int b = c >> 7;
        int j = atomicAdd(&scur[b], 1);
        pay[j] = make_int2(r | ((c & 127) << 17) | ((b & 0xFF) << 24),
                           (int)((wb & ~3u) | ((unsigned)b >> 8)));
    }
    __syncthreads();
    for (int j = tid; j < EPB; j += 1024) {
        int2 q = pay[j];
        int b = (int)((((unsigned)q.y & 3u) << 8) | (((unsigned)q.x >> 24) & 0xFFu));
        int pos = gbase[b] + (j - hexc[b]);
        tre[pos] = make_int2(q.x & 0x00FFFFFF, q.y & ~3);
    }
}

// per bucket: stage in LDS, count + weighted-degree + scan, write dinv and
// rowptr, emit node-sorted 4B packed edges: src(17b) | sign-free bf16(ew)(15b).
__global__ __launch_bounds__(512)
void sort_k(const int2* __restrict__ tre, const int* __restrict__ scanned,
            unsigned int* __restrict__ srn4, int* __restrict__ rowptr,
            float* __restrict__ dinv) {
    __shared__ int2 ed[BCAP];      // 40 KB
    __shared__ int h[128];
    __shared__ float dw[128];
    __shared__ int sc[128];
    __shared__ int cur[128];
    int b = blockIdx.x, tid = threadIdx.x;
    int base = scanned[b * NBLK];
    int end = (b == NBKT - 1) ? NE : scanned[(b + 1) * NBLK];
    int n = end - base;
    bool staged = (n <= BCAP);
    if (tid < 128) { h[tid] = 0; dw[tid] = 0.f; }
    if (staged)
        for (int i = tid; i < n; i += 512) ed[i] = tre[base + i];
    __syncthreads();
    for (int i = tid; i < n; i += 512) {
        int2 q = staged ? ed[i] : tre[base + i];
        int key = (q.x >> 17) & 127;
        atomicAdd(&h[key], 1);
        atomicAdd(&dw[key], __int_as_float(q.y));
    }
    __syncthreads();
    if (tid < 128) sc[tid] = h[tid];
    __syncthreads();
    for (int off = 1; off < 128; off <<= 1) {
        int v = (tid < 128 && tid >= off) ? sc[tid - off] : 0;
        __syncthreads();
        if (tid < 128) sc[tid] += v;
        __syncthreads();
    }
    if (tid < 128) {
        int node = b * 128 + tid;
        if (node < NN) {
            rowptr[node] = base + sc[tid];               // end offset
            dinv[node] = rsqrtf(1.0f + dw[tid]);         // self-loop included
        }
        cur[tid] = base + sc[tid] - h[tid];              // start cursor
    }
    __syncthreads();
    for (int i = tid; i < n; i += 512) {
        int2 q = staged ? ed[i] : tre[base + i];
        int key = (q.x >> 17) & 127;
        int pos = atomicAdd(&cur[key], 1);
        unsigned int wb = (unsigned)q.y;                 // positive ew bits
        wb += 0x7FFFu + ((wb >> 16) & 1u);               // RNE to bf16
        srn4[pos] = (unsigned)(q.x & SRCMASK) | (((wb >> 16) & 0x7FFFu) << 17);
    }
}

// LDS-tiled linear: 64-row x tile; W pre-swizzled; thread = 2 rows x 4
// contiguous cols; output = fp8(dinv[row] * acc) (dinv folded in, so edge
// messages need only ew and aggregate's epilogue applies dinv[dst] once).
template <int IN_DIM, bool RELU_IN>
__global__ __launch_bounds__(256)
void linear_k(const float* __restrict__ in, const float* __restrict__ W,
              const float* __restrict__ dinv, unsigned int* __restrict__ tmp8) {
    constexpr int J4 = IN_DIM / 4;       // 32 or 8
    constexpr int XSS = J4 + 1;          // padded row stride (float4)
    __shared__ float4 xs[64 * XSS];
    __shared__ float4 wp[IN_DIM * 8];
    int tid = threadIdx.x;
    for (int idx = tid; idx < IN_DIM * 8; idx += 256) {
        int j = idx >> 3, kg = idx & 7;
        const float* wr = W + j * 32 + kg * 4;
        wp[idx] = make_float4(wr[0], wr[1], wr[2], wr[3]);
    }
    int rbase = blockIdx.x * 64;
    const float4* in4 = (const float4*)in;
    for (int idx = tid; idx < 64 * J4; idx += 256) {
        int row = idx / J4, j4 = idx % J4;
        int grow = rbase + row;
        float4 v = (grow < NN) ? in4[(size_t)grow * J4 + j4]
                               : make_float4(0.f, 0.f, 0.f, 0.f);
        if (RELU_IN) {
            v.x = fmaxf(v.x, 0.f); v.y = fmaxf(v.y, 0.f);
            v.z = fmaxf(v.z, 0.f); v.w = fmaxf(v.w, 0.f);
        }
        xs[row * XSS + j4] = v;
    }
    __syncthreads();
    int kg = tid & 7;          // cols 4kg..4kg+3
    int rp = tid >> 3;         // rows 2rp, 2rp+1
    int r0 = rbase + 2 * rp;
    if (r0 >= NN) return;
    const float4* x0 = &xs[(2 * rp) * XSS];
    const float4* x1 = &xs[(2 * rp + 1) * XSS];
    float a00 = 0, a01 = 0, a02 = 0, a03 = 0;
    float a10 = 0, a11 = 0, a12 = 0, a13 = 0;
#pragma unroll
    for (int j4 = 0; j4 < J4; ++j4) {
        float4 v0 = x0[j4], v1 = x1[j4];
        const float4* wj = &wp[j4 * 4 * 8 + kg];
        float4 w0 = wj[0], w1 = wj[8], w2 = wj[16], w3 = wj[24];
#define LSTEP(VX0, VX1, W4) \
        a00 = fmaf(VX0, W4.x, a00); a01 = fmaf(VX0, W4.y, a01); \
        a02 = fmaf(VX0, W4.z, a02); a03 = fmaf(VX0, W4.w, a03); \
        a10 = fmaf(VX1, W4.x, a10); a11 = fmaf(VX1, W4.y, a11); \
        a12 = fmaf(VX1, W4.z, a12); a13 = fmaf(VX1, W4.w, a13);
        LSTEP(v0.x, v1.x, w0)
        LSTEP(v0.y, v1.y, w1)
        LSTEP(v0.z, v1.z, w2)
        LSTEP(v0.w, v1.w, w3)
#undef LSTEP
    }
    float d0 = dinv[r0], d1 = dinv[r0 + 1];
    a00 *= d0; a01 *= d0; a02 *= d0; a03 *= d0;
    a10 *= d1; a11 *= d1; a12 *= d1; a13 *= d1;
    int q0 = __builtin_amdgcn_cvt_pk_fp8_f32(a00, a01, 0, false);
    q0 = __builtin_amdgcn_cvt_pk_fp8_f32(a02, a03, q0, true);
    int q1 = __builtin_amdgcn_cvt_pk_fp8_f32(a10, a11, 0, false);
    q1 = __builtin_amdgcn_cvt_pk_fp8_f32(a12, a13, q1, true);
    tmp8[r0 * 8 + kg] = (unsigned int)q0;
    tmp8[(r0 + 1) * 8 + kg] = (unsigned int)q1;
}

// one wave per dest node: 8 edge slots x 8 feat-quads (R11 structure, proven),
// deepened to 4 prefetched srn4 loads + 4 gathers per burst (stride 32 =
// mean degree, so most nodes finish in one fully-in-flight burst).
// h = bias + dinv[dst] * (self_scaled + sum(ew * msg_scaled)).
__global__ void aggregate(const unsigned int* __restrict__ srn4,
                          const int* __restrict__ rowptr,
                          const float* __restrict__ dinv,
                          const float* __restrict__ bias,
                          const unsigned int* __restrict__ tmp8,
                          float* __restrict__ h) {
    int wid = (blockIdx.x * 256 + threadIdx.x) >> 6;
    if (wid >= NN) return;
    int lane = threadIdx.x & 63;
    int g = lane >> 3;      // edge slot 0..7
    int q = lane & 7;       // feat quad (feats 4q..4q+3)
    int end = rowptr[wid];
    int start = (wid == 0) ? 0 : rowptr[wid - 1];
    float a0 = 0, a1 = 0, a2 = 0, a3 = 0;
    float b0 = 0, b1 = 0, b2 = 0, b3 = 0;
    int e = start + g;
    for (; e + 24 < end; e += 32) {
        unsigned int p0 = srn4[e];
        unsigned int p1 = srn4[e + 8];
        unsigned int p2 = srn4[e + 16];
        unsigned int p3 = srn4[e + 24];
        unsigned int u0 = tmp8[(size_t)(p0 & SRCMASK) * 8 + q];
        unsigned int u1 = tmp8[(size_t)(p1 & SRCMASK) * 8 + q];
        unsigned int u2 = tmp8[(size_t)(p2 & SRCMASK) * 8 + q];
        unsigned int u3 = tmp8[(size_t)(p3 & SRCMASK) * 8 + q];
        float w0 = __uint_as_float((p0 >> 1) & 0x7FFF0000u);
        float w1 = __uint_as_float((p1 >> 1) & 0x7FFF0000u);
        float w2 = __uint_as_float((p2 >> 1) & 0x7FFF0000u);
        float w3 = __uint_as_float((p3 >> 1) & 0x7FFF0000u);
        floatx2 lo, hi;
        lo = __builtin_amdgcn_cvt_pk_f32_fp8(u0, false);
        hi = __builtin_amdgcn_cvt_pk_f32_fp8(u0, true);
        a0 = fmaf(w0, lo.x, a0); a1 = fmaf(w0, lo.y, a1);
        a2 = fmaf(w0, hi.x, a2); a3 = fmaf(w0, hi.y, a3);
        lo = __builtin_amdgcn_cvt_pk_f32_fp8(u1, false);
        hi = __builtin_amdgcn_cvt_pk_f32_fp8(u1, true);
        b0 = fmaf(w1, lo.x, b0); b1 = fmaf(w1, lo.y, b1);
        b2 = fmaf(w1, hi.x, b2); b3 = fmaf(w1, hi.y, b3);
        lo = __builtin_amdgcn_cvt_pk_f32_fp8(u2, false);
        hi = __builtin_amdgcn_cvt_pk_f32_fp8(u2, true);
        a0 = fmaf(w2, lo.x, a0); a1 = fmaf(w2, lo.y, a1);
        a2 = fmaf(w2, hi.x, a2); a3 = fmaf(w2, hi.y, a3);
        lo = __builtin_amdgcn_cvt_pk_f32_fp8(u3, false);
        hi = __builtin_amdgcn_cvt_pk_f32_fp8(u3, true);
        b0 = fmaf(w3, lo.x, b0); b1 = fmaf(w3, lo.y, b1);
        b2 = fmaf(w3, hi.x, b2); b3 = fmaf(w3, hi.y, b3);
    }
    for (; e < end; e += 8) {
        unsigned int p = srn4[e];
        unsigned int u = tmp8[(size_t)(p & SRCMASK) * 8 + q];
        float w = __uint_as_float((p >> 1) & 0x7FFF0000u);
        floatx2 lo = __builtin_amdgcn_cvt_pk_f32_fp8(u, false);
        floatx2 hi = __builtin_amdgcn_cvt_pk_f32_fp8(u, true);
        a0 = fmaf(w, lo.x, a0); a1 = fmaf(w, lo.y, a1);
        a2 = fmaf(w, hi.x, a2); a3 = fmaf(w, hi.y, a3);
    }
    a0 += b0; a1 += b1; a2 += b2; a3 += b3;
    a0 += __shfl_xor(a0, 8, 64); a1 += __shfl_xor(a1, 8, 64);
    a2 += __shfl_xor(a2, 8, 64); a3 += __shfl_xor(a3, 8, 64);
    a0 += __shfl_xor(a0, 16, 64); a1 += __shfl_xor(a1, 16, 64);
    a2 += __shfl_xor(a2, 16, 64); a3 += __shfl_xor(a3, 16, 64);
    a0 += __shfl_xor(a0, 32, 64); a1 += __shfl_xor(a1, 32, 64);
    a2 += __shfl_xor(a2, 32, 64); a3 += __shfl_xor(a3, 32, 64);
    if (g == 0) {
        float d = dinv[wid];
        unsigned int sv = tmp8[(size_t)wid * 8 + q];
        floatx2 slo = __builtin_amdgcn_cvt_pk_f32_fp8(sv, false);
        floatx2 shi = __builtin_amdgcn_cvt_pk_f32_fp8(sv, true);
        float4 bq = ((const float4*)bias)[q];
        float4 o;
        o.x = bq.x + d * (slo.x + a0);
        o.y = bq.y + d * (slo.y + a1);
        o.z = bq.z + d * (shi.x + a2);
        o.w = bq.w + d * (shi.y + a3);
        ((float4*)(h + (size_t)wid * HID))[q] = o;
    }
}

// one block per graph: binary-search the sorted batch for boundaries,
// stride-accumulate, LDS-reduce. No atomics, no init pass needed.
__global__ __launch_bounds__(256)
void pool_k(const float* __restrict__ h, const int* __restrict__ batch,
            float* __restrict__ sums, float* __restrict__ counts) {
    __shared__ float red[256];
    int g = blockIdx.x;
    int lo = 0, hi = NN;
    while (lo < hi) { int m = (lo + hi) >> 1; if (batch[m] < g) lo = m + 1; else hi = m; }
    int s = lo;
    lo = s; hi = NN;
    while (lo < hi) { int m = (lo + hi) >> 1; if (batch[m] < g + 1) lo = m + 1; else hi = m; }
    int e2 = lo;
    int tid = threadIdx.x;
    int r = tid >> 5, k = tid & 31;   // 8 rows x 32 feats
    float acc = 0.f;
    for (int i = s + r; i < e2; i += 8) acc += h[(size_t)i * HID + k];
    red[tid] = acc;
    __syncthreads();
    for (int off = 128; off >= 32; off >>= 1) {
        if (tid < off) red[tid] += red[tid + off];
        __syncthreads();
    }
    if (tid < 32) sums[g * HID + tid] = red[tid];
    if (tid == 0) counts[g] = (float)(e2 - s);
}

// MLP: one block per graph, one wave; thread k owns output column k.
__global__ __launch_bounds__(64)
void mlp_k(const float* __restrict__ sums, const float* __restrict__ counts,
           const float* __restrict__ Wm0, const float* __restrict__ bm0,
           const float* __restrict__ Wm1, const float* __restrict__ bm1,
           const float* __restrict__ Wout, const float* __restrict__ bout,
           float* __restrict__ out) {
    __shared__ float g0[HID];
    __shared__ float g1[MH];
    __shared__ float g2[MH];
    int g = blockIdx.x;       // 0..63
    int k = threadIdx.x;      // 0..63
    if (k < HID) g0[k] = sums[g * HID + k] / fmaxf(counts[g], 1.0f);
    __syncthreads();
    float acc = bm0[k];
#pragma unroll
    for (int j = 0; j < HID; ++j) acc = fmaf(g0[j], Wm0[j * MH + k], acc);
    g1[k] = fmaxf(acc, 0.f);
    __syncthreads();
    float acc2 = bm1[k];
#pragma unroll
    for (int j = 0; j < MH; ++j) acc2 = fmaf(g1[j], Wm1[j * MH + k], acc2);
    g2[k] = fmaxf(acc2, 0.f);
    __syncthreads();
    if (k < NC) {
        float acc3 = bout[k];
#pragma unroll
        for (int j = 0; j < MH; ++j) acc3 = fmaf(g2[j], Wout[j * NC + k], acc3);
        out[g * NC + k] = acc3;
    }
}

extern "C" void kernel_launch(void* const* d_in, const int* in_sizes, int n_in,
                              void* d_out, int out_size, void* d_ws, size_t ws_size,
                              hipStream_t stream) {
    const float* x    = (const float*)d_in[0];
    const int*   ei   = (const int*)d_in[1];
    const float* ew   = (const float*)d_in[2];
    const int*   batch= (const int*)d_in[3];
    const float* W1   = (const float*)d_in[4];
    const float* b1   = (const float*)d_in[5];
    const float* W2   = (const float*)d_in[6];
    const float* b2   = (const float*)d_in[7];
    const float* W3   = (const float*)d_in[8];
    const float* b3   = (const float*)d_in[9];
    const float* Wm0  = (const float*)d_in[10];
    const float* bm0  = (const float*)d_in[11];
    const float* Wm1  = (const float*)d_in[12];
    const float* bm1  = (const float*)d_in[13];
    const float* Wout = (const float*)d_in[14];
    const float* bout = (const float*)d_in[15];
    float* out = (float*)d_out;

    // workspace: srn4 | S (tre+cnt2+scanned <-> tmp8+hA+hB) | small bufs
    char* p = (char*)d_ws;
    unsigned int* srn4 = (unsigned int*)p; p += sizeof(unsigned int) * (size_t)NE; // 12.8 MB
    char*  S   = p;                      p += 12 * (size_t)NE;                // 38.4 MB shared
    int2*  tre = (int2*)S;                                                    // 25.6 MB
    int*   cnt2    = (int*)(S + sizeof(int2) * (size_t)NE);                   // 1.6 MB (dies pre-layer1)
    int*   scanned = cnt2 + SCANL;                                            // 1.6 MB
    unsigned int* tmp8 = (unsigned int*)S;                                    // 3.2 MB
    float* hA  = (float*)(S + (size_t)NN * HID);                              // 12.8 MB
    float* hB  = hA + (size_t)NN * HID;                                       // 12.8 MB
    int*   bsum    = (int*)p;            p += sizeof(int) * 512;
    float* dinv    = (float*)p;          p += sizeof(float) * NN;
    int*   rowptr  = (int*)p;            p += sizeof(int) * NN;
    float* sums    = (float*)p;          p += sizeof(float) * NG * HID;
    float* counts  = (float*)p;

    dim3 blk(256);
    const int NB_SCAN = (SCANL + 1023) / 1024;  // 391
    const int NB_LIN = (NN + 63) / 64;          // 1563

    hist_bkt<<<NBLK, 1024, 0, stream>>>(ei, cnt2);
    scan_block<<<NB_SCAN, blk, 0, stream>>>(cnt2, scanned, bsum, SCANL);
    scan_top<<<1, 64, 0, stream>>>(bsum, NB_SCAN);
    scan_add<<<(SCANL + 255) / 256, blk, 0, stream>>>(scanned, bsum, SCANL);
    scatter_bkt<<<NBLK, 1024, 0, stream>>>(ei, ew, cnt2, scanned, tre);
    sort_k<<<NBKT, 512, 0, stream>>>(tre, scanned, srn4, rowptr, dinv);

    // layer 1
    linear_k<FIN, false><<<NB_LIN, blk, 0, stream>>>(x, W1, dinv, tmp8);
    aggregate<<<25000, blk, 0, stream>>>(srn4, rowptr, dinv, b1, tmp8, hA);
    // layer 2
    linear_k<HID, true><<<NB_LIN, blk, 0, stream>>>(hA, W2, dinv, tmp8);
    aggregate<<<25000, blk, 0, stream>>>(srn4, rowptr, dinv, b2, tmp8, hB);
    // layer 3
    linear_k<HID, true><<<NB_LIN, blk, 0, stream>>>(hB, W3, dinv, tmp8);
    aggregate<<<25000, blk, 0, stream>>>(srn4, rowptr, dinv, b3, tmp8, hA);

    pool_k<<<NG, blk, 0, stream>>>(hA, batch, sums, counts);
    mlp_k<<<NG, 64, 0, stream>>>(sums, counts, Wm0, bm0, Wm1, bm1, Wout, bout, out);
}

// Round 14
// 413.651 us; speedup vs baseline: 1.0668x; 1.0668x over previous
//
#include <hip/hip_runtime.h>

#define NN 100000
#define NE 3200000
#define FIN 128
#define HID 32
#define MH  64
#define NC  10
#define NG  64
#define NBKT 782           // ceil(NN/128) buckets of 128 dest nodes
#define NBLK 512           // edge-pass blocks
#define EPB  (NE / NBLK)   // 6250 edges per block
#define SCANL (NBKT * NBLK)
#define SRCMASK 0x1FFFF    // src < 100000 < 2^17
#define BCAP 5120          // bucket LDS capacity (mean 4092, sd ~64)

typedef float floatx2 __attribute__((ext_vector_type(2)));

// per-block LDS histogram over 782 dest-buckets; no global atomics
__global__ __launch_bounds__(1024)
void hist_bkt(const int* __restrict__ ei, int* __restrict__ cnt2) {
    __shared__ int h[NBKT];
    int tid = threadIdx.x, blk = blockIdx.x;
    for (int b = tid; b < NBKT; b += 1024) h[b] = 0;
    __syncthreads();
    int base = blk * EPB;
    for (int i = tid; i < EPB; i += 1024)
        atomicAdd(&h[ei[NE + base + i] >> 7], 1);
    __syncthreads();
    for (int b = tid; b < NBKT; b += 1024) cnt2[b * NBLK + blk] = h[b];
}

// ---- generic exclusive scan (1024 elems/block) ----
__global__ void scan_block(const int* __restrict__ in, int* __restrict__ out,
                           int* __restrict__ bsum, int n) {
    __shared__ int lds[256];
    int tid = threadIdx.x;
    int base = blockIdx.x * 1024 + tid * 4;
    int v0 = 0, v1 = 0, v2 = 0, v3 = 0;
    if (base + 0 < n) v0 = in[base + 0];
    if (base + 1 < n) v1 = in[base + 1];
    if (base + 2 < n) v2 = in[base + 2];
    if (base + 3 < n) v3 = in[base + 3];
    int s = v0 + v1 + v2 + v3;
    lds[tid] = s;
    __syncthreads();
    for (int off = 1; off < 256; off <<= 1) {
        int val = (tid >= off) ? lds[tid - off] : 0;
        __syncthreads();
        lds[tid] += val;
        __syncthreads();
    }
    int excl = lds[tid] - s;
    if (tid == 255) bsum[blockIdx.x] = lds[255];
    if (base + 0 < n) out[base + 0] = excl;
    if (base + 1 < n) out[base + 1] = excl + v0;
    if (base + 2 < n) out[base + 2] = excl + v0 + v1;
    if (base + 3 < n) out[base + 3] = excl + v0 + v1 + v2;
}

// wave-parallel exclusive scan of bsum; also zeroes pooled sums+counts
// (they're only written much later by pool_k's atomics).
__global__ void scan_top(int* __restrict__ bsum, int nb, float* __restrict__ sc) {
    int lane = threadIdx.x;  // 64 threads
    for (int i = lane; i < NG * HID + NG; i += 64) sc[i] = 0.0f;
    int carry = 0;
    for (int base = 0; base < nb; base += 64) {
        int i = base + lane;
        int orig = (i < nb) ? bsum[i] : 0;
        int v = orig;
#pragma unroll
        for (int off = 1; off < 64; off <<= 1) {
            int t = __shfl_up(v, off, 64);
            if (lane >= off) v += t;
        }
        if (i < nb) bsum[i] = carry + v - orig;   // exclusive
        carry += __shfl(v, 63, 64);
    }
}

__global__ void scan_add(int* __restrict__ data, const int* __restrict__ bsum, int n) {
    int i = blockIdx.x * 256 + threadIdx.x;
    if (i < n) data[i] += bsum[i >> 10];
}

// single global read: pack each edge into LDS at its sorted slot, then
// slot-major burst writes to tre.
__global__ __launch_bounds__(1024)
void scatter_bkt(const int* __restrict__ ei, const float* __restrict__ ew,
                 const int* __restrict__ cnt2, const int* __restrict__ scanned,
                 int2* __restrict__ tre) {
    __shared__ int2 pay[EPB];      // 50 KB
    __shared__ int scur[NBKT];
    __shared__ int hexc[NBKT];
    __shared__ int gbase[NBKT];
    int tid = threadIdx.x, blk = blockIdx.x;
    int myh = 0;
    if (tid < NBKT) {
        myh = cnt2[tid * NBLK + blk];
        gbase[tid] = scanned[tid * NBLK + blk];
        scur[tid] = myh;
    }
    __syncthreads();
    for (int off = 1; off < NBKT; off <<= 1) {
        int v = (tid < NBKT && tid >= off) ? scur[tid - off] : 0;
        __syncthreads();
        if (tid < NBKT) scur[tid] += v;
        __syncthreads();
    }
    if (tid < NBKT) { int ex = scur[tid] - myh; hexc[tid] = ex; scur[tid] = ex; }
    __syncthreads();
    int base = blk * EPB;
    for (int i = tid; i < EPB; i += 1024) {
        int e = base + i;
        int c = ei[NE + e];
        int r = ei[e];
        unsigned int wb = __float_as_uint(ew[e]);
        int b = c >> 7;
        int j = atomicAdd(&scur[b], 1);
        pay[j] = make_int2(r | ((c & 127) << 17) | ((b & 0xFF) << 24),
                           (int)((wb & ~3u) | ((unsigned)b >> 8)));
    }
    __syncthreads();
    for (int j = tid; j < EPB; j += 1024) {
        int2 q = pay[j];
        int b = (int)((((unsigned)q.y & 3u) << 8) | (((unsigned)q.x >> 24) & 0xFFu));
        int pos = gbase[b] + (j - hexc[b]);
        tre[pos] = make_int2(q.x & 0x00FFFFFF, q.y & ~3);
    }
}

// per bucket: stage in LDS, count + weighted-degree + scan, write dinv and
// rowptr, emit node-sorted 4B packed edges: src(17b) | sign-free bf16(ew)(15b).
__global__ __launch_bounds__(512)
void sort_k(const int2* __restrict__ tre, const int* __restrict__ scanned,
            unsigned int* __restrict__ srn4, int* __restrict__ rowptr,
            float* __restrict__ dinv) {
    __shared__ int2 ed[BCAP];      // 40 KB
    __shared__ int h[128];
    __shared__ float dw[128];
    __shared__ int sc[128];
    __shared__ int cur[128];
    int b = blockIdx.x, tid = threadIdx.x;
    int base = scanned[b * NBLK];
    int end = (b == NBKT - 1) ? NE : scanned[(b + 1) * NBLK];
    int n = end - base;
    bool staged = (n <= BCAP);
    if (tid < 128) { h[tid] = 0; dw[tid] = 0.f; }
    if (staged)
        for (int i = tid; i < n; i += 512) ed[i] = tre[base + i];
    __syncthreads();
    for (int i = tid; i < n; i += 512) {
        int2 q = staged ? ed[i] : tre[base + i];
        int key = (q.x >> 17) & 127;
        atomicAdd(&h[key], 1);
        atomicAdd(&dw[key], __int_as_float(q.y));
    }
    __syncthreads();
    if (tid < 128) sc[tid] = h[tid];
    __syncthreads();
    for (int off = 1; off < 128; off <<= 1) {
        int v = (tid < 128 && tid >= off) ? sc[tid - off] : 0;
        __syncthreads();
        if (tid < 128) sc[tid] += v;
        __syncthreads();
    }
    if (tid < 128) {
        int node = b * 128 + tid;
        if (node < NN) {
            rowptr[node] = base + sc[tid];               // end offset
            dinv[node] = rsqrtf(1.0f + dw[tid]);         // self-loop included
        }
        cur[tid] = base + sc[tid] - h[tid];              // start cursor
    }
    __syncthreads();
    for (int i = tid; i < n; i += 512) {
        int2 q = staged ? ed[i] : tre[base + i];
        int key = (q.x >> 17) & 127;
        int pos = atomicAdd(&cur[key], 1);
        unsigned int wb = (unsigned)q.y;                 // positive ew bits
        wb += 0x7FFFu + ((wb >> 16) & 1u);               // RNE to bf16
        srn4[pos] = (unsigned)(q.x & SRCMASK) | (((wb >> 16) & 0x7FFFu) << 17);
    }
}

// LDS-tiled linear: 64-row x tile; W pre-swizzled; thread = 2 rows x 4
// contiguous cols; output = fp8(dinv[row] * acc) (dinv folded in).
template <int IN_DIM, bool RELU_IN>
__global__ __launch_bounds__(256)
void linear_k(const float* __restrict__ in, const float* __restrict__ W,
              const float* __restrict__ dinv, unsigned int* __restrict__ tmp8) {
    constexpr int J4 = IN_DIM / 4;       // 32 or 8
    constexpr int XSS = J4 + 1;          // padded row stride (float4)
    __shared__ float4 xs[64 * XSS];
    __shared__ float4 wp[IN_DIM * 8];
    int tid = threadIdx.x;
    for (int idx = tid; idx < IN_DIM * 8; idx += 256) {
        int j = idx >> 3, kg = idx & 7;
        const float* wr = W + j * 32 + kg * 4;
        wp[idx] = make_float4(wr[0], wr[1], wr[2], wr[3]);
    }
    int rbase = blockIdx.x * 64;
    const float4* in4 = (const float4*)in;
    for (int idx = tid; idx < 64 * J4; idx += 256) {
        int row = idx / J4, j4 = idx % J4;
        int grow = rbase + row;
        float4 v = (grow < NN) ? in4[(size_t)grow * J4 + j4]
                               : make_float4(0.f, 0.f, 0.f, 0.f);
        if (RELU_IN) {
            v.x = fmaxf(v.x, 0.f); v.y = fmaxf(v.y, 0.f);
            v.z = fmaxf(v.z, 0.f); v.w = fmaxf(v.w, 0.f);
        }
        xs[row * XSS + j4] = v;
    }
    __syncthreads();
    int kg = tid & 7;          // cols 4kg..4kg+3
    int rp = tid >> 3;         // rows 2rp, 2rp+1
    int r0 = rbase + 2 * rp;
    if (r0 >= NN) return;
    const float4* x0 = &xs[(2 * rp) * XSS];
    const float4* x1 = &xs[(2 * rp + 1) * XSS];
    float a00 = 0, a01 = 0, a02 = 0, a03 = 0;
    float a10 = 0, a11 = 0, a12 = 0, a13 = 0;
#pragma unroll
    for (int j4 = 0; j4 < J4; ++j4) {
        float4 v0 = x0[j4], v1 = x1[j4];
        const float4* wj = &wp[j4 * 4 * 8 + kg];
        float4 w0 = wj[0], w1 = wj[8], w2 = wj[16], w3 = wj[24];
#define LSTEP(VX0, VX1, W4) \
        a00 = fmaf(VX0, W4.x, a00); a01 = fmaf(VX0, W4.y, a01); \
        a02 = fmaf(VX0, W4.z, a02); a03 = fmaf(VX0, W4.w, a03); \
        a10 = fmaf(VX1, W4.x, a10); a11 = fmaf(VX1, W4.y, a11); \
        a12 = fmaf(VX1, W4.z, a12); a13 = fmaf(VX1, W4.w, a13);
        LSTEP(v0.x, v1.x, w0)
        LSTEP(v0.y, v1.y, w1)
        LSTEP(v0.z, v1.z, w2)
        LSTEP(v0.w, v1.w, w3)
#undef LSTEP
    }
    float d0 = dinv[r0], d1 = dinv[r0 + 1];
    a00 *= d0; a01 *= d0; a02 *= d0; a03 *= d0;
    a10 *= d1; a11 *= d1; a12 *= d1; a13 *= d1;
    int q0 = __builtin_amdgcn_cvt_pk_fp8_f32(a00, a01, 0, false);
    q0 = __builtin_amdgcn_cvt_pk_fp8_f32(a02, a03, q0, true);
    int q1 = __builtin_amdgcn_cvt_pk_fp8_f32(a10, a11, 0, false);
    q1 = __builtin_amdgcn_cvt_pk_fp8_f32(a12, a13, q1, true);
    tmp8[r0 * 8 + kg] = (unsigned int)q0;
    tmp8[(r0 + 1) * 8 + kg] = (unsigned int)q1;
}

// one wave per dest node: 8 edge slots x 8 feat-quads, burst of 4 prefetched
// srn4 loads + 4 gathers (stride 32 = mean degree).
// h = bias + dinv[dst] * (self_scaled + sum(ew * msg_scaled)).
__global__ void aggregate(const unsigned int* __restrict__ srn4,
                          const int* __restrict__ rowptr,
                          const float* __restrict__ dinv,
                          const float* __restrict__ bias,
                          const unsigned int* __restrict__ tmp8,
                          float* __restrict__ h) {
    int wid = (blockIdx.x * 256 + threadIdx.x) >> 6;
    if (wid >= NN) return;
    int lane = threadIdx.x & 63;
    int g = lane >> 3;      // edge slot 0..7
    int q = lane & 7;       // feat quad (feats 4q..4q+3)
    int end = rowptr[wid];
    int start = (wid == 0) ? 0 : rowptr[wid - 1];
    float a0 = 0, a1 = 0, a2 = 0, a3 = 0;
    float b0 = 0, b1 = 0, b2 = 0, b3 = 0;
    int e = start + g;
    for (; e + 24 < end; e += 32) {
        unsigned int p0 = srn4[e];
        unsigned int p1 = srn4[e + 8];
        unsigned int p2 = srn4[e + 16];
        unsigned int p3 = srn4[e + 24];
        unsigned int u0 = tmp8[(size_t)(p0 & SRCMASK) * 8 + q];
        unsigned int u1 = tmp8[(size_t)(p1 & SRCMASK) * 8 + q];
        unsigned int u2 = tmp8[(size_t)(p2 & SRCMASK) * 8 + q];
        unsigned int u3 = tmp8[(size_t)(p3 & SRCMASK) * 8 + q];
        float w0 = __uint_as_float((p0 >> 1) & 0x7FFF0000u);
        float w1 = __uint_as_float((p1 >> 1) & 0x7FFF0000u);
        float w2 = __uint_as_float((p2 >> 1) & 0x7FFF0000u);
        float w3 = __uint_as_float((p3 >> 1) & 0x7FFF0000u);
        floatx2 lo, hi;
        lo = __builtin_amdgcn_cvt_pk_f32_fp8(u0, false);
        hi = __builtin_amdgcn_cvt_pk_f32_fp8(u0, true);
        a0 = fmaf(w0, lo.x, a0); a1 = fmaf(w0, lo.y, a1);
        a2 = fmaf(w0, hi.x, a2); a3 = fmaf(w0, hi.y, a3);
        lo = __builtin_amdgcn_cvt_pk_f32_fp8(u1, false);
        hi = __builtin_amdgcn_cvt_pk_f32_fp8(u1, true);
        b0 = fmaf(w1, lo.x, b0); b1 = fmaf(w1, lo.y, b1);
        b2 = fmaf(w1, hi.x, b2); b3 = fmaf(w1, hi.y, b3);
        lo = __builtin_amdgcn_cvt_pk_f32_fp8(u2, false);
        hi = __builtin_amdgcn_cvt_pk_f32_fp8(u2, true);
        a0 = fmaf(w2, lo.x, a0); a1 = fmaf(w2, lo.y, a1);
        a2 = fmaf(w2, hi.x, a2); a3 = fmaf(w2, hi.y, a3);
        lo = __builtin_amdgcn_cvt_pk_f32_fp8(u3, false);
        hi = __builtin_amdgcn_cvt_pk_f32_fp8(u3, true);
        b0 = fmaf(w3, lo.x, b0); b1 = fmaf(w3, lo.y, b1);
        b2 = fmaf(w3, hi.x, b2); b3 = fmaf(w3, hi.y, b3);
    }
    for (; e < end; e += 8) {
        unsigned int p = srn4[e];
        unsigned int u = tmp8[(size_t)(p & SRCMASK) * 8 + q];
        float w = __uint_as_float((p >> 1) & 0x7FFF0000u);
        floatx2 lo = __builtin_amdgcn_cvt_pk_f32_fp8(u, false);
        floatx2 hi = __builtin_amdgcn_cvt_pk_f32_fp8(u, true);
        a0 = fmaf(w, lo.x, a0); a1 = fmaf(w, lo.y, a1);
        a2 = fmaf(w, hi.x, a2); a3 = fmaf(w, hi.y, a3);
    }
    a0 += b0; a1 += b1; a2 += b2; a3 += b3;
    a0 += __shfl_xor(a0, 8, 64); a1 += __shfl_xor(a1, 8, 64);
    a2 += __shfl_xor(a2, 8, 64); a3 += __shfl_xor(a3, 8, 64);
    a0 += __shfl_xor(a0, 16, 64); a1 += __shfl_xor(a1, 16, 64);
    a2 += __shfl_xor(a2, 16, 64); a3 += __shfl_xor(a3, 16, 64);
    a0 += __shfl_xor(a0, 32, 64); a1 += __shfl_xor(a1, 32, 64);
    a2 += __shfl_xor(a2, 32, 64); a3 += __shfl_xor(a3, 32, 64);
    if (g == 0) {
        float d = dinv[wid];
        unsigned int sv = tmp8[(size_t)wid * 8 + q];
        floatx2 slo = __builtin_amdgcn_cvt_pk_f32_fp8(sv, false);
        floatx2 shi = __builtin_amdgcn_cvt_pk_f32_fp8(sv, true);
        float4 bq = ((const float4*)bias)[q];
        float4 o;
        o.x = bq.x + d * (slo.x + a0);
        o.y = bq.y + d * (slo.y + a1);
        o.z = bq.z + d * (shi.x + a2);
        o.w = bq.w + d * (shi.y + a3);
        ((float4*)(h + (size_t)wid * HID))[q] = o;
    }
}

// sorted-batch run-length pooling (R12 structure: 3125 chunks x 32 nodes,
// per-thread run-length accumulation, boundary atomics only)
__global__ void pool_k(const float* __restrict__ h, const int* __restrict__ batch,
                       float* __restrict__ sums, float* __restrict__ counts) {
    int t = blockIdx.x * 256 + threadIdx.x;
    int chunk = t >> 5, k = t & 31;
    int n0 = chunk * 32;
    if (n0 >= NN) return;
    int n1 = min(n0 + 32, NN);
    int g = batch[n0];
    float acc = 0.f, cacc = 0.f;
    for (int i = n0; i < n1; ++i) {
        int gi = batch[i];
        if (gi != g) {
            atomicAdd(&sums[g * HID + k], acc);
            if (k == 0) atomicAdd(&counts[g], cacc);
            g = gi; acc = 0.f; cacc = 0.f;
        }
        acc += h[(size_t)i * HID + k];
        cacc += 1.f;
    }
    atomicAdd(&sums[g * HID + k], acc);
    if (k == 0) atomicAdd(&counts[g], cacc);
}

// MLP: one block per graph, one wave; thread k owns output column k.
__global__ __launch_bounds__(64)
void mlp_k(const float* __restrict__ sums, const float* __restrict__ counts,
           const float* __restrict__ Wm0, const float* __restrict__ bm0,
           const float* __restrict__ Wm1, const float* __restrict__ bm1,
           const float* __restrict__ Wout, const float* __restrict__ bout,
           float* __restrict__ out) {
    __shared__ float g0[HID];
    __shared__ float g1[MH];
    __shared__ float g2[MH];
    int g = blockIdx.x;       // 0..63
    int k = threadIdx.x;      // 0..63
    if (k < HID) g0[k] = sums[g * HID + k] / fmaxf(counts[g], 1.0f);
    __syncthreads();
    float acc = bm0[k];
#pragma unroll
    for (int j = 0; j < HID; ++j) acc = fmaf(g0[j], Wm0[j * MH + k], acc);
    g1[k] = fmaxf(acc, 0.f);
    __syncthreads();
    float acc2 = bm1[k];
#pragma unroll
    for (int j = 0; j < MH; ++j) acc2 = fmaf(g1[j], Wm1[j * MH + k], acc2);
    g2[k] = fmaxf(acc2, 0.f);
    __syncthreads();
    if (k < NC) {
        float acc3 = bout[k];
#pragma unroll
        for (int j = 0; j < MH; ++j) acc3 = fmaf(g2[j], Wout[j * NC + k], acc3);
        out[g * NC + k] = acc3;
    }
}

extern "C" void kernel_launch(void* const* d_in, const int* in_sizes, int n_in,
                              void* d_out, int out_size, void* d_ws, size_t ws_size,
                              hipStream_t stream) {
    const float* x    = (const float*)d_in[0];
    const int*   ei   = (const int*)d_in[1];
    const float* ew   = (const float*)d_in[2];
    const int*   batch= (const int*)d_in[3];
    const float* W1   = (const float*)d_in[4];
    const float* b1   = (const float*)d_in[5];
    const float* W2   = (const float*)d_in[6];
    const float* b2   = (const float*)d_in[7];
    const float* W3   = (const float*)d_in[8];
    const float* b3   = (const float*)d_in[9];
    const float* Wm0  = (const float*)d_in[10];
    const float* bm0  = (const float*)d_in[11];
    const float* Wm1  = (const float*)d_in[12];
    const float* bm1  = (const float*)d_in[13];
    const float* Wout = (const float*)d_in[14];
    const float* bout = (const float*)d_in[15];
    float* out = (float*)d_out;

    // workspace: srn4 | S (tre+cnt2+scanned <-> tmp8+hA+hB) | small bufs
    char* p = (char*)d_ws;
    unsigned int* srn4 = (unsigned int*)p; p += sizeof(unsigned int) * (size_t)NE; // 12.8 MB
    char*  S   = p;                      p += 12 * (size_t)NE;                // 38.4 MB shared
    int2*  tre = (int2*)S;                                                    // 25.6 MB
    int*   cnt2    = (int*)(S + sizeof(int2) * (size_t)NE);                   // 1.6 MB (dies pre-layer1)
    int*   scanned = cnt2 + SCANL;                                            // 1.6 MB
    unsigned int* tmp8 = (unsigned int*)S;                                    // 3.2 MB
    float* hA  = (float*)(S + (size_t)NN * HID);                              // 12.8 MB
    float* hB  = hA + (size_t)NN * HID;                                       // 12.8 MB
    int*   bsum    = (int*)p;            p += sizeof(int) * 512;
    float* dinv    = (float*)p;          p += sizeof(float) * NN;
    int*   rowptr  = (int*)p;            p += sizeof(int) * NN;
    float* sums    = (float*)p;          p += sizeof(float) * NG * HID;
    float* counts  = (float*)p;

    dim3 blk(256);
    const int NB_SCAN = (SCANL + 1023) / 1024;  // 391
    const int NB_LIN = (NN + 63) / 64;          // 1563

    hist_bkt<<<NBLK, 1024, 0, stream>>>(ei, cnt2);
    scan_block<<<NB_SCAN, blk, 0, stream>>>(cnt2, scanned, bsum, SCANL);
    scan_top<<<1, 64, 0, stream>>>(bsum, NB_SCAN, sums);  // also zeroes sums+counts
    scan_add<<<(SCANL + 255) / 256, blk, 0, stream>>>(scanned, bsum, SCANL);
    scatter_bkt<<<NBLK, 1024, 0, stream>>>(ei, ew, cnt2, scanned, tre);
    sort_k<<<NBKT, 512, 0, stream>>>(tre, scanned, srn4, rowptr, dinv);

    // layer 1
    linear_k<FIN, false><<<NB_LIN, blk, 0, stream>>>(x, W1, dinv, tmp8);
    aggregate<<<25000, blk, 0, stream>>>(srn4, rowptr, dinv, b1, tmp8, hA);
    // layer 2
    linear_k<HID, true><<<NB_LIN, blk, 0, stream>>>(hA, W2, dinv, tmp8);
    aggregate<<<25000, blk, 0, stream>>>(srn4, rowptr, dinv, b2, tmp8, hB);
    // layer 3
    linear_k<HID, true><<<NB_LIN, blk, 0, stream>>>(hB, W3, dinv, tmp8);
    aggregate<<<25000, blk, 0, stream>>>(srn4, rowptr, dinv, b3, tmp8, hA);

    pool_k<<<391, blk, 0, stream>>>(hA, batch, sums, counts);
    mlp_k<<<NG, 64, 0, stream>>>(sums, counts, Wm0, bm0, Wm1, bm1, Wout, bout, out);
}

// Round 15
// 405.816 us; speedup vs baseline: 1.0873x; 1.0193x over previous
//
#include <hip/hip_runtime.h>

#define NN 100000
#define NE 3200000
#define FIN 128
#define HID 32
#define MH  64
#define NC  10
#define NG  64
#define NBKT 782           // ceil(NN/128) buckets of 128 dest nodes
#define NBLK 512           // edge-pass blocks
#define EPB  (NE / NBLK)   // 6250 edges per block
#define SCANL (NBKT * NBLK)
#define SRCMASK 0x1FFFF    // src < 100000 < 2^17
#define BCAP 5120          // bucket LDS capacity (mean 4092, sd ~64)

typedef float floatx2 __attribute__((ext_vector_type(2)));

// per-block LDS histogram over 782 dest-buckets; no global atomics
__global__ __launch_bounds__(1024)
void hist_bkt(const int* __restrict__ ei, int* __restrict__ cnt2) {
    __shared__ int h[NBKT];
    int tid = threadIdx.x, blk = blockIdx.x;
    for (int b = tid; b < NBKT; b += 1024) h[b] = 0;
    __syncthreads();
    int base = blk * EPB;
    for (int i = tid; i < EPB; i += 1024)
        atomicAdd(&h[ei[NE + base + i] >> 7], 1);
    __syncthreads();
    for (int b = tid; b < NBKT; b += 1024) cnt2[b * NBLK + blk] = h[b];
}

// ---- generic exclusive scan (1024 elems/block) ----
__global__ void scan_block(const int* __restrict__ in, int* __restrict__ out,
                           int* __restrict__ bsum, int n) {
    __shared__ int lds[256];
    int tid = threadIdx.x;
    int base = blockIdx.x * 1024 + tid * 4;
    int v0 = 0, v1 = 0, v2 = 0, v3 = 0;
    if (base + 0 < n) v0 = in[base + 0];
    if (base + 1 < n) v1 = in[base + 1];
    if (base + 2 < n) v2 = in[base + 2];
    if (base + 3 < n) v3 = in[base + 3];
    int s = v0 + v1 + v2 + v3;
    lds[tid] = s;
    __syncthreads();
    for (int off = 1; off < 256; off <<= 1) {
        int val = (tid >= off) ? lds[tid - off] : 0;
        __syncthreads();
        lds[tid] += val;
        __syncthreads();
    }
    int excl = lds[tid] - s;
    if (tid == 255) bsum[blockIdx.x] = lds[255];
    if (base + 0 < n) out[base + 0] = excl;
    if (base + 1 < n) out[base + 1] = excl + v0;
    if (base + 2 < n) out[base + 2] = excl + v0 + v1;
    if (base + 3 < n) out[base + 3] = excl + v0 + v1 + v2;
}

// wave-parallel exclusive scan of bsum; also zeroes pooled sums+counts
__global__ void scan_top(int* __restrict__ bsum, int nb, float* __restrict__ sc) {
    int lane = threadIdx.x;  // 64 threads
    for (int i = lane; i < NG * HID + NG; i += 64) sc[i] = 0.0f;
    int carry = 0;
    for (int base = 0; base < nb; base += 64) {
        int i = base + lane;
        int orig = (i < nb) ? bsum[i] : 0;
        int v = orig;
#pragma unroll
        for (int off = 1; off < 64; off <<= 1) {
            int t = __shfl_up(v, off, 64);
            if (lane >= off) v += t;
        }
        if (i < nb) bsum[i] = carry + v - orig;   // exclusive
        carry += __shfl(v, 63, 64);
    }
}

__global__ void scan_add(int* __restrict__ data, const int* __restrict__ bsum, int n) {
    int i = blockIdx.x * 256 + threadIdx.x;
    if (i < n) data[i] += bsum[i >> 10];
}

// single global read: pack each edge into LDS at its sorted slot, then
// slot-major burst writes to tre.
__global__ __launch_bounds__(1024)
void scatter_bkt(const int* __restrict__ ei, const float* __restrict__ ew,
                 const int* __restrict__ cnt2, const int* __restrict__ scanned,
                 int2* __restrict__ tre) {
    __shared__ int2 pay[EPB];      // 50 KB
    __shared__ int scur[NBKT];
    __shared__ int hexc[NBKT];
    __shared__ int gbase[NBKT];
    int tid = threadIdx.x, blk = blockIdx.x;
    int myh = 0;
    if (tid < NBKT) {
        myh = cnt2[tid * NBLK + blk];
        gbase[tid] = scanned[tid * NBLK + blk];
        scur[tid] = myh;
    }
    __syncthreads();
    for (int off = 1; off < NBKT; off <<= 1) {
        int v = (tid < NBKT && tid >= off) ? scur[tid - off] : 0;
        __syncthreads();
        if (tid < NBKT) scur[tid] += v;
        __syncthreads();
    }
    if (tid < NBKT) { int ex = scur[tid] - myh; hexc[tid] = ex; scur[tid] = ex; }
    __syncthreads();
    int base = blk * EPB;
    for (int i = tid; i < EPB; i += 1024) {
        int e = base + i;
        int c = ei[NE + e];
        int r = ei[e];
        unsigned int wb = __float_as_uint(ew[e]);
        int b = c >> 7;
        int j = atomicAdd(&scur[b], 1);
        pay[j] = make_int2(r | ((c & 127) << 17) | ((b & 0xFF) << 24),
                           (int)((wb & ~3u) | ((unsigned)b >> 8)));
    }
    __syncthreads();
    for (int j = tid; j < EPB; j += 1024) {
        int2 q = pay[j];
        int b = (int)((((unsigned)q.y & 3u) << 8) | (((unsigned)q.x >> 24) & 0xFFu));
        int pos = gbase[b] + (j - hexc[b]);
        tre[pos] = make_int2(q.x & 0x00FFFFFF, q.y & ~3);
    }
}

// per bucket, lean: pass1 fuses stage+count+weighted-degree; wave-0 shuffle
// scan of 128 bins writes rowptr+dinv; pass2 emits node-sorted 4B edges.
// 3 barriers total (was ~20).
__global__ __launch_bounds__(512)
void sort_k(const int2* __restrict__ tre, const int* __restrict__ scanned,
            unsigned int* __restrict__ srn4, int* __restrict__ rowptr,
            float* __restrict__ dinv) {
    __shared__ int2 ed[BCAP];      // 40 KB
    __shared__ int h[128];
    __shared__ float dw[128];
    __shared__ int cur[128];
    int b = blockIdx.x, tid = threadIdx.x;
    int base = scanned[b * NBLK];
    int end = (b == NBKT - 1) ? NE : scanned[(b + 1) * NBLK];
    int n = end - base;
    bool staged = (n <= BCAP);
    if (tid < 128) { h[tid] = 0; dw[tid] = 0.f; }
    __syncthreads();
    // pass 1: single global read, fused stage + histogram + weighted degree
    for (int i = tid; i < n; i += 512) {
        int2 q = tre[base + i];
        if (staged) ed[i] = q;
        int key = (q.x >> 17) & 127;
        atomicAdd(&h[key], 1);
        atomicAdd(&dw[key], __int_as_float(q.y));
    }
    __syncthreads();
    // wave-0 scan: 128 bins as 2 chunks of 64 with carry
    if (tid < 64) {
        int lane = tid;
        int carry = 0;
#pragma unroll
        for (int c = 0; c < 2; ++c) {
            int idx = c * 64 + lane;
            int hv = h[idx];
            int v = hv;
#pragma unroll
            for (int off = 1; off < 64; off <<= 1) {
                int t = __shfl_up(v, off, 64);
                if (lane >= off) v += t;
            }
            cur[idx] = base + carry + v - hv;           // start cursor
            int node = b * 128 + idx;
            if (node < NN) {
                rowptr[node] = base + carry + v;        // end offset
                dinv[node] = rsqrtf(1.0f + dw[idx]);    // self-loop included
            }
            carry += __shfl(v, 63, 64);
        }
    }
    __syncthreads();
    // pass 2: emit sorted packed edges
    for (int i = tid; i < n; i += 512) {
        int2 q = staged ? ed[i] : tre[base + i];
        int key = (q.x >> 17) & 127;
        int pos = atomicAdd(&cur[key], 1);
        unsigned int wb = (unsigned)q.y;                // positive ew bits
        wb += 0x7FFFu + ((wb >> 16) & 1u);              // RNE to bf16
        srn4[pos] = (unsigned)(q.x & SRCMASK) | (((wb >> 16) & 0x7FFFu) << 17);
    }
}

// LDS-tiled linear: 64-row x tile; W pre-swizzled; thread = 2 rows x 4
// contiguous cols; output = fp8(dinv[row] * acc) (dinv folded in).
template <int IN_DIM, bool RELU_IN>
__global__ __launch_bounds__(256)
void linear_k(const float* __restrict__ in, const float* __restrict__ W,
              const float* __restrict__ dinv, unsigned int* __restrict__ tmp8) {
    constexpr int J4 = IN_DIM / 4;       // 32 or 8
    constexpr int XSS = J4 + 1;          // padded row stride (float4)
    __shared__ float4 xs[64 * XSS];
    __shared__ float4 wp[IN_DIM * 8];
    int tid = threadIdx.x;
    for (int idx = tid; idx < IN_DIM * 8; idx += 256) {
        int j = idx >> 3, kg = idx & 7;
        const float* wr = W + j * 32 + kg * 4;
        wp[idx] = make_float4(wr[0], wr[1], wr[2], wr[3]);
    }
    int rbase = blockIdx.x * 64;
    const float4* in4 = (const float4*)in;
    for (int idx = tid; idx < 64 * J4; idx += 256) {
        int row = idx / J4, j4 = idx % J4;
        int grow = rbase + row;
        float4 v = (grow < NN) ? in4[(size_t)grow * J4 + j4]
                               : make_float4(0.f, 0.f, 0.f, 0.f);
        if (RELU_IN) {
            v.x = fmaxf(v.x, 0.f); v.y = fmaxf(v.y, 0.f);
            v.z = fmaxf(v.z, 0.f); v.w = fmaxf(v.w, 0.f);
        }
        xs[row * XSS + j4] = v;
    }
    __syncthreads();
    int kg = tid & 7;          // cols 4kg..4kg+3
    int rp = tid >> 3;         // rows 2rp, 2rp+1
    int r0 = rbase + 2 * rp;
    if (r0 >= NN) return;
    const float4* x0 = &xs[(2 * rp) * XSS];
    const float4* x1 = &xs[(2 * rp + 1) * XSS];
    float a00 = 0, a01 = 0, a02 = 0, a03 = 0;
    float a10 = 0, a11 = 0, a12 = 0, a13 = 0;
#pragma unroll
    for (int j4 = 0; j4 < J4; ++j4) {
        float4 v0 = x0[j4], v1 = x1[j4];
        const float4* wj = &wp[j4 * 4 * 8 + kg];
        float4 w0 = wj[0], w1 = wj[8], w2 = wj[16], w3 = wj[24];
#define LSTEP(VX0, VX1, W4) \
        a00 = fmaf(VX0, W4.x, a00); a01 = fmaf(VX0, W4.y, a01); \
        a02 = fmaf(VX0, W4.z, a02); a03 = fmaf(VX0, W4.w, a03); \
        a10 = fmaf(VX1, W4.x, a10); a11 = fmaf(VX1, W4.y, a11); \
        a12 = fmaf(VX1, W4.z, a12); a13 = fmaf(VX1, W4.w, a13);
        LSTEP(v0.x, v1.x, w0)
        LSTEP(v0.y, v1.y, w1)
        LSTEP(v0.z, v1.z, w2)
        LSTEP(v0.w, v1.w, w3)
#undef LSTEP
    }
    float d0 = dinv[r0], d1 = dinv[r0 + 1];
    a00 *= d0; a01 *= d0; a02 *= d0; a03 *= d0;
    a10 *= d1; a11 *= d1; a12 *= d1; a13 *= d1;
    int q0 = __builtin_amdgcn_cvt_pk_fp8_f32(a00, a01, 0, false);
    q0 = __builtin_amdgcn_cvt_pk_fp8_f32(a02, a03, q0, true);
    int q1 = __builtin_amdgcn_cvt_pk_fp8_f32(a10, a11, 0, false);
    q1 = __builtin_amdgcn_cvt_pk_fp8_f32(a12, a13, q1, true);
    tmp8[r0 * 8 + kg] = (unsigned int)q0;
    tmp8[(r0 + 1) * 8 + kg] = (unsigned int)q1;
}

// one wave per dest node: 8 edge slots x 8 feat-quads, burst of 4 prefetched
// srn4 loads + 4 gathers (stride 32 = mean degree).
// h = bias + dinv[dst] * (self_scaled + sum(ew * msg_scaled)).
__global__ void aggregate(const unsigned int* __restrict__ srn4,
                          const int* __restrict__ rowptr,
                          const float* __restrict__ dinv,
                          const float* __restrict__ bias,
                          const unsigned int* __restrict__ tmp8,
                          float* __restrict__ h) {
    int wid = (blockIdx.x * 256 + threadIdx.x) >> 6;
    if (wid >= NN) return;
    int lane = threadIdx.x & 63;
    int g = lane >> 3;      // edge slot 0..7
    int q = lane & 7;       // feat quad (feats 4q..4q+3)
    int end = rowptr[wid];
    int start = (wid == 0) ? 0 : rowptr[wid - 1];
    float a0 = 0, a1 = 0, a2 = 0, a3 = 0;
    float b0 = 0, b1 = 0, b2 = 0, b3 = 0;
    int e = start + g;
    for (; e + 24 < end; e += 32) {
        unsigned int p0 = srn4[e];
        unsigned int p1 = srn4[e + 8];
        unsigned int p2 = srn4[e + 16];
        unsigned int p3 = srn4[e + 24];
        unsigned int u0 = tmp8[(size_t)(p0 & SRCMASK) * 8 + q];
        unsigned int u1 = tmp8[(size_t)(p1 & SRCMASK) * 8 + q];
        unsigned int u2 = tmp8[(size_t)(p2 & SRCMASK) * 8 + q];
        unsigned int u3 = tmp8[(size_t)(p3 & SRCMASK) * 8 + q];
        float w0 = __uint_as_float((p0 >> 1) & 0x7FFF0000u);
        float w1 = __uint_as_float((p1 >> 1) & 0x7FFF0000u);
        float w2 = __uint_as_float((p2 >> 1) & 0x7FFF0000u);
        float w3 = __uint_as_float((p3 >> 1) & 0x7FFF0000u);
        floatx2 lo, hi;
        lo = __builtin_amdgcn_cvt_pk_f32_fp8(u0, false);
        hi = __builtin_amdgcn_cvt_pk_f32_fp8(u0, true);
        a0 = fmaf(w0, lo.x, a0); a1 = fmaf(w0, lo.y, a1);
        a2 = fmaf(w0, hi.x, a2); a3 = fmaf(w0, hi.y, a3);
        lo = __builtin_amdgcn_cvt_pk_f32_fp8(u1, false);
        hi = __builtin_amdgcn_cvt_pk_f32_fp8(u1, true);
        b0 = fmaf(w1, lo.x, b0); b1 = fmaf(w1, lo.y, b1);
        b2 = fmaf(w1, hi.x, b2); b3 = fmaf(w1, hi.y, b3);
        lo = __builtin_amdgcn_cvt_pk_f32_fp8(u2, false);
        hi = __builtin_amdgcn_cvt_pk_f32_fp8(u2, true);
        a0 = fmaf(w2, lo.x, a0); a1 = fmaf(w2, lo.y, a1);
        a2 = fmaf(w2, hi.x, a2); a3 = fmaf(w2, hi.y, a3);
        lo = __builtin_amdgcn_cvt_pk_f32_fp8(u3, false);
        hi = __builtin_amdgcn_cvt_pk_f32_fp8(u3, true);
        b0 = fmaf(w3, lo.x, b0); b1 = fmaf(w3, lo.y, b1);
        b2 = fmaf(w3, hi.x, b2); b3 = fmaf(w3, hi.y, b3);
    }
    for (; e < end; e += 8) {
        unsigned int p = srn4[e];
        unsigned int u = tmp8[(size_t)(p & SRCMASK) * 8 + q];
        float w = __uint_as_float((p >> 1) & 0x7FFF0000u);
        floatx2 lo = __builtin_amdgcn_cvt_pk_f32_fp8(u, false);
        floatx2 hi = __builtin_amdgcn_cvt_pk_f32_fp8(u, true);
        a0 = fmaf(w, lo.x, a0); a1 = fmaf(w, lo.y, a1);
        a2 = fmaf(w, hi.x, a2); a3 = fmaf(w, hi.y, a3);
    }
    a0 += b0; a1 += b1; a2 += b2; a3 += b3;
    a0 += __shfl_xor(a0, 8, 64); a1 += __shfl_xor(a1, 8, 64);
    a2 += __shfl_xor(a2, 8, 64); a3 += __shfl_xor(a3, 8, 64);
    a0 += __shfl_xor(a0, 16, 64); a1 += __shfl_xor(a1, 16, 64);
    a2 += __shfl_xor(a2, 16, 64); a3 += __shfl_xor(a3, 16, 64);
    a0 += __shfl_xor(a0, 32, 64); a1 += __shfl_xor(a1, 32, 64);
    a2 += __shfl_xor(a2, 32, 64); a3 += __shfl_xor(a3, 32, 64);
    if (g == 0) {
        float d = dinv[wid];
        unsigned int sv = tmp8[(size_t)wid * 8 + q];
        floatx2 slo = __builtin_amdgcn_cvt_pk_f32_fp8(sv, false);
        floatx2 shi = __builtin_amdgcn_cvt_pk_f32_fp8(sv, true);
        float4 bq = ((const float4*)bias)[q];
        float4 o;
        o.x = bq.x + d * (slo.x + a0);
        o.y = bq.y + d * (slo.y + a1);
        o.z = bq.z + d * (shi.x + a2);
        o.w = bq.w + d * (shi.y + a3);
        ((float4*)(h + (size_t)wid * HID))[q] = o;
    }
}

// sorted-batch run-length pooling (3125 chunks x 32 nodes, boundary atomics)
__global__ void pool_k(const float* __restrict__ h, const int* __restrict__ batch,
                       float* __restrict__ sums, float* __restrict__ counts) {
    int t = blockIdx.x * 256 + threadIdx.x;
    int chunk = t >> 5, k = t & 31;
    int n0 = chunk * 32;
    if (n0 >= NN) return;
    int n1 = min(n0 + 32, NN);
    int g = batch[n0];
    float acc = 0.f, cacc = 0.f;
    for (int i = n0; i < n1; ++i) {
        int gi = batch[i];
        if (gi != g) {
            atomicAdd(&sums[g * HID + k], acc);
            if (k == 0) atomicAdd(&counts[g], cacc);
            g = gi; acc = 0.f; cacc = 0.f;
        }
        acc += h[(size_t)i * HID + k];
        cacc += 1.f;
    }
    atomicAdd(&sums[g * HID + k], acc);
    if (k == 0) atomicAdd(&counts[g], cacc);
}

// MLP: one block per graph, one wave; thread k owns output column k.
__global__ __launch_bounds__(64)
void mlp_k(const float* __restrict__ sums, const float* __restrict__ counts,
           const float* __restrict__ Wm0, const float* __restrict__ bm0,
           const float* __restrict__ Wm1, const float* __restrict__ bm1,
           const float* __restrict__ Wout, const float* __restrict__ bout,
           float* __restrict__ out) {
    __shared__ float g0[HID];
    __shared__ float g1[MH];
    __shared__ float g2[MH];
    int g = blockIdx.x;       // 0..63
    int k = threadIdx.x;      // 0..63
    if (k < HID) g0[k] = sums[g * HID + k] / fmaxf(counts[g], 1.0f);
    __syncthreads();
    float acc = bm0[k];
#pragma unroll
    for (int j = 0; j < HID; ++j) acc = fmaf(g0[j], Wm0[j * MH + k], acc);
    g1[k] = fmaxf(acc, 0.f);
    __syncthreads();
    float acc2 = bm1[k];
#pragma unroll
    for (int j = 0; j < MH; ++j) acc2 = fmaf(g1[j], Wm1[j * MH + k], acc2);
    g2[k] = fmaxf(acc2, 0.f);
    __syncthreads();
    if (k < NC) {
        float acc3 = bout[k];
#pragma unroll
        for (int j = 0; j < MH; ++j) acc3 = fmaf(g2[j], Wout[j * NC + k], acc3);
        out[g * NC + k] = acc3;
    }
}

extern "C" void kernel_launch(void* const* d_in, const int* in_sizes, int n_in,
                              void* d_out, int out_size, void* d_ws, size_t ws_size,
                              hipStream_t stream) {
    const float* x    = (const float*)d_in[0];
    const int*   ei   = (const int*)d_in[1];
    const float* ew   = (const float*)d_in[2];
    const int*   batch= (const int*)d_in[3];
    const float* W1   = (const float*)d_in[4];
    const float* b1   = (const float*)d_in[5];
    const float* W2   = (const float*)d_in[6];
    const float* b2   = (const float*)d_in[7];
    const float* W3   = (const float*)d_in[8];
    const float* b3   = (const float*)d_in[9];
    const float* Wm0  = (const float*)d_in[10];
    const float* bm0  = (const float*)d_in[11];
    const float* Wm1  = (const float*)d_in[12];
    const float* bm1  = (const float*)d_in[13];
    const float* Wout = (const float*)d_in[14];
    const float* bout = (const float*)d_in[15];
    float* out = (float*)d_out;

    // workspace: srn4 | S (tre+cnt2+scanned <-> tmp8+hA+hB) | small bufs
    char* p = (char*)d_ws;
    unsigned int* srn4 = (unsigned int*)p; p += sizeof(unsigned int) * (size_t)NE; // 12.8 MB
    char*  S   = p;                      p += 12 * (size_t)NE;                // 38.4 MB shared
    int2*  tre = (int2*)S;                                                    // 25.6 MB
    int*   cnt2    = (int*)(S + sizeof(int2) * (size_t)NE);                   // 1.6 MB (dies pre-layer1)
    int*   scanned = cnt2 + SCANL;                                            // 1.6 MB
    unsigned int* tmp8 = (unsigned int*)S;                                    // 3.2 MB
    float* hA  = (float*)(S + (size_t)NN * HID);                              // 12.8 MB
    float* hB  = hA + (size_t)NN * HID;                                       // 12.8 MB
    int*   bsum    = (int*)p;            p += sizeof(int) * 512;
    float* dinv    = (float*)p;          p += sizeof(float) * NN;
    int*   rowptr  = (int*)p;            p += sizeof(int) * NN;
    float* sums    = (float*)p;          p += sizeof(float) * NG * HID;
    float* counts  = (float*)p;

    dim3 blk(256);
    const int NB_SCAN = (SCANL + 1023) / 1024;  // 391
    const int NB_LIN = (NN + 63) / 64;          // 1563

    hist_bkt<<<NBLK, 1024, 0, stream>>>(ei, cnt2);
    scan_block<<<NB_SCAN, blk, 0, stream>>>(cnt2, scanned, bsum, SCANL);
    scan_top<<<1, 64, 0, stream>>>(bsum, NB_SCAN, sums);  // also zeroes sums+counts
    scan_add<<<(SCANL + 255) / 256, blk, 0, stream>>>(scanned, bsum, SCANL);
    scatter_bkt<<<NBLK, 1024, 0, stream>>>(ei, ew, cnt2, scanned, tre);
    sort_k<<<NBKT, 512, 0, stream>>>(tre, scanned, srn4, rowptr, dinv);

    // layer 1
    linear_k<FIN, false><<<NB_LIN, blk, 0, stream>>>(x, W1, dinv, tmp8);
    aggregate<<<25000, blk, 0, stream>>>(srn4, rowptr, dinv, b1, tmp8, hA);
    // layer 2
    linear_k<HID, true><<<NB_LIN, blk, 0, stream>>>(hA, W2, dinv, tmp8);
    aggregate<<<25000, blk, 0, stream>>>(srn4, rowptr, dinv, b2, tmp8, hB);
    // layer 3
    linear_k<HID, true><<<NB_LIN, blk, 0, stream>>>(hB, W3, dinv, tmp8);
    aggregate<<<25000, blk, 0, stream>>>(srn4, rowptr, dinv, b3, tmp8, hA);

    pool_k<<<391, blk, 0, stream>>>(hA, batch, sums, counts);
    mlp_k<<<NG, 64, 0, stream>>>(sums, counts, Wm0, bm0, Wm1, bm1, Wout, bout, out);
}

// Round 16
// 404.214 us; speedup vs baseline: 1.0917x; 1.0040x over previous
//
#include <hip/hip_runtime.h>

#define NN 100000
#define NE 3200000
#define FIN 128
#define HID 32
#define MH  64
#define NC  10
#define NG  64
#define NBKT 782           // ceil(NN/128) buckets of 128 dest nodes
#define NBLK 512           // edge-pass blocks
#define EPB  (NE / NBLK)   // 6250 edges per block
#define SCANL (NBKT * NBLK)
#define SRCMASK 0x1FFFF    // src < 100000 < 2^17
#define BCAP 5120          // bucket LDS capacity (mean 4092, sd ~64)

typedef float floatx2 __attribute__((ext_vector_type(2)));

// per-block LDS histogram over 782 dest-buckets; no global atomics
__global__ __launch_bounds__(1024)
void hist_bkt(const int* __restrict__ ei, int* __restrict__ cnt2) {
    __shared__ int h[NBKT];
    int tid = threadIdx.x, blk = blockIdx.x;
    for (int b = tid; b < NBKT; b += 1024) h[b] = 0;
    __syncthreads();
    int base = blk * EPB;
    for (int i = tid; i < EPB; i += 1024)
        atomicAdd(&h[ei[NE + base + i] >> 7], 1);
    __syncthreads();
    for (int b = tid; b < NBKT; b += 1024) cnt2[b * NBLK + blk] = h[b];
}

// ---- generic exclusive scan (1024 elems/block) ----
__global__ void scan_block(const int* __restrict__ in, int* __restrict__ out,
                           int* __restrict__ bsum, int n) {
    __shared__ int lds[256];
    int tid = threadIdx.x;
    int base = blockIdx.x * 1024 + tid * 4;
    int v0 = 0, v1 = 0, v2 = 0, v3 = 0;
    if (base + 0 < n) v0 = in[base + 0];
    if (base + 1 < n) v1 = in[base + 1];
    if (base + 2 < n) v2 = in[base + 2];
    if (base + 3 < n) v3 = in[base + 3];
    int s = v0 + v1 + v2 + v3;
    lds[tid] = s;
    __syncthreads();
    for (int off = 1; off < 256; off <<= 1) {
        int val = (tid >= off) ? lds[tid - off] : 0;
        __syncthreads();
        lds[tid] += val;
        __syncthreads();
    }
    int excl = lds[tid] - s;
    if (tid == 255) bsum[blockIdx.x] = lds[255];
    if (base + 0 < n) out[base + 0] = excl;
    if (base + 1 < n) out[base + 1] = excl + v0;
    if (base + 2 < n) out[base + 2] = excl + v0 + v1;
    if (base + 3 < n) out[base + 3] = excl + v0 + v1 + v2;
}

// wave-parallel exclusive scan of bsum; also zeroes pooled sums+counts
__global__ void scan_top(int* __restrict__ bsum, int nb, float* __restrict__ sc) {
    int lane = threadIdx.x;  // 64 threads
    for (int i = lane; i < NG * HID + NG; i += 64) sc[i] = 0.0f;
    int carry = 0;
    for (int base = 0; base < nb; base += 64) {
        int i = base + lane;
        int orig = (i < nb) ? bsum[i] : 0;
        int v = orig;
#pragma unroll
        for (int off = 1; off < 64; off <<= 1) {
            int t = __shfl_up(v, off, 64);
            if (lane >= off) v += t;
        }
        if (i < nb) bsum[i] = carry + v - orig;   // exclusive
        carry += __shfl(v, 63, 64);
    }
}

__global__ void scan_add(int* __restrict__ data, const int* __restrict__ bsum, int n) {
    int i = blockIdx.x * 256 + threadIdx.x;
    if (i < n) data[i] += bsum[i >> 10];
}

// single global read: pack each edge into LDS at its sorted slot, then
// slot-major burst writes to tre.
__global__ __launch_bounds__(1024)
void scatter_bkt(const int* __restrict__ ei, const float* __restrict__ ew,
                 const int* __restrict__ cnt2, const int* __restrict__ scanned,
                 int2* __restrict__ tre) {
    __shared__ int2 pay[EPB];      // 50 KB
    __shared__ int scur[NBKT];
    __shared__ int hexc[NBKT];
    __shared__ int gbase[NBKT];
    int tid = threadIdx.x, blk = blockIdx.x;
    int myh = 0;
    if (tid < NBKT) {
        myh = cnt2[tid * NBLK + blk];
        gbase[tid] = scanned[tid * NBLK + blk];
        scur[tid] = myh;
    }
    __syncthreads();
    for (int off = 1; off < NBKT; off <<= 1) {
        int v = (tid < NBKT && tid >= off) ? scur[tid - off] : 0;
        __syncthreads();
        if (tid < NBKT) scur[tid] += v;
        __syncthreads();
    }
    if (tid < NBKT) { int ex = scur[tid] - myh; hexc[tid] = ex; scur[tid] = ex; }
    __syncthreads();
    int base = blk * EPB;
    for (int i = tid; i < EPB; i += 1024) {
        int e = base + i;
        int c = ei[NE + e];
        int r = ei[e];
        unsigned int wb = __float_as_uint(ew[e]);
        int b = c >> 7;
        int j = atomicAdd(&scur[b], 1);
        pay[j] = make_int2(r | ((c & 127) << 17) | ((b & 0xFF) << 24),
                           (int)((wb & ~3u) | ((unsigned)b >> 8)));
    }
    __syncthreads();
    for (int j = tid; j < EPB; j += 1024) {
        int2 q = pay[j];
        int b = (int)((((unsigned)q.y & 3u) << 8) | (((unsigned)q.x >> 24) & 0xFFu));
        int pos = gbase[b] + (j - hexc[b]);
        tre[pos] = make_int2(q.x & 0x00FFFFFF, q.y & ~3);
    }
}

// per bucket, lean: pass1 fuses stage+count+weighted-degree; wave-0 shuffle
// scan of 128 bins writes rowptr+dinv; pass2 emits node-sorted 4B edges.
__global__ __launch_bounds__(512)
void sort_k(const int2* __restrict__ tre, const int* __restrict__ scanned,
            unsigned int* __restrict__ srn4, int* __restrict__ rowptr,
            float* __restrict__ dinv) {
    __shared__ int2 ed[BCAP];      // 40 KB
    __shared__ int h[128];
    __shared__ float dw[128];
    __shared__ int cur[128];
    int b = blockIdx.x, tid = threadIdx.x;
    int base = scanned[b * NBLK];
    int end = (b == NBKT - 1) ? NE : scanned[(b + 1) * NBLK];
    int n = end - base;
    bool staged = (n <= BCAP);
    if (tid < 128) { h[tid] = 0; dw[tid] = 0.f; }
    __syncthreads();
    for (int i = tid; i < n; i += 512) {
        int2 q = tre[base + i];
        if (staged) ed[i] = q;
        int key = (q.x >> 17) & 127;
        atomicAdd(&h[key], 1);
        atomicAdd(&dw[key], __int_as_float(q.y));
    }
    __syncthreads();
    if (tid < 64) {
        int lane = tid;
        int carry = 0;
#pragma unroll
        for (int c = 0; c < 2; ++c) {
            int idx = c * 64 + lane;
            int hv = h[idx];
            int v = hv;
#pragma unroll
            for (int off = 1; off < 64; off <<= 1) {
                int t = __shfl_up(v, off, 64);
                if (lane >= off) v += t;
            }
            cur[idx] = base + carry + v - hv;           // start cursor
            int node = b * 128 + idx;
            if (node < NN) {
                rowptr[node] = base + carry + v;        // end offset
                dinv[node] = rsqrtf(1.0f + dw[idx]);    // self-loop included
            }
            carry += __shfl(v, 63, 64);
        }
    }
    __syncthreads();
    for (int i = tid; i < n; i += 512) {
        int2 q = staged ? ed[i] : tre[base + i];
        int key = (q.x >> 17) & 127;
        int pos = atomicAdd(&cur[key], 1);
        unsigned int wb = (unsigned)q.y;                // positive ew bits
        wb += 0x7FFFu + ((wb >> 16) & 1u);              // RNE to bf16
        srn4[pos] = (unsigned)(q.x & SRCMASK) | (((wb >> 16) & 0x7FFFu) << 17);
    }
}

// LDS-tiled linear (layer 1 only): 64-row x tile; W pre-swizzled; thread =
// 2 rows x 4 contiguous cols; output = fp8(dinv[row] * acc).
template <int IN_DIM, bool RELU_IN>
__global__ __launch_bounds__(256)
void linear_k(const float* __restrict__ in, const float* __restrict__ W,
              const float* __restrict__ dinv, unsigned int* __restrict__ tmp8) {
    constexpr int J4 = IN_DIM / 4;
    constexpr int XSS = J4 + 1;
    __shared__ float4 xs[64 * XSS];
    __shared__ float4 wp[IN_DIM * 8];
    int tid = threadIdx.x;
    for (int idx = tid; idx < IN_DIM * 8; idx += 256) {
        int j = idx >> 3, kg = idx & 7;
        const float* wr = W + j * 32 + kg * 4;
        wp[idx] = make_float4(wr[0], wr[1], wr[2], wr[3]);
    }
    int rbase = blockIdx.x * 64;
    const float4* in4 = (const float4*)in;
    for (int idx = tid; idx < 64 * J4; idx += 256) {
        int row = idx / J4, j4 = idx % J4;
        int grow = rbase + row;
        float4 v = (grow < NN) ? in4[(size_t)grow * J4 + j4]
                               : make_float4(0.f, 0.f, 0.f, 0.f);
        if (RELU_IN) {
            v.x = fmaxf(v.x, 0.f); v.y = fmaxf(v.y, 0.f);
            v.z = fmaxf(v.z, 0.f); v.w = fmaxf(v.w, 0.f);
        }
        xs[row * XSS + j4] = v;
    }
    __syncthreads();
    int kg = tid & 7;
    int rp = tid >> 3;
    int r0 = rbase + 2 * rp;
    if (r0 >= NN) return;
    const float4* x0 = &xs[(2 * rp) * XSS];
    const float4* x1 = &xs[(2 * rp + 1) * XSS];
    float a00 = 0, a01 = 0, a02 = 0, a03 = 0;
    float a10 = 0, a11 = 0, a12 = 0, a13 = 0;
#pragma unroll
    for (int j4 = 0; j4 < J4; ++j4) {
        float4 v0 = x0[j4], v1 = x1[j4];
        const float4* wj = &wp[j4 * 4 * 8 + kg];
        float4 w0 = wj[0], w1 = wj[8], w2 = wj[16], w3 = wj[24];
#define LSTEP(VX0, VX1, W4) \
        a00 = fmaf(VX0, W4.x, a00); a01 = fmaf(VX0, W4.y, a01); \
        a02 = fmaf(VX0, W4.z, a02); a03 = fmaf(VX0, W4.w, a03); \
        a10 = fmaf(VX1, W4.x, a10); a11 = fmaf(VX1, W4.y, a11); \
        a12 = fmaf(VX1, W4.z, a12); a13 = fmaf(VX1, W4.w, a13);
        LSTEP(v0.x, v1.x, w0)
        LSTEP(v0.y, v1.y, w1)
        LSTEP(v0.z, v1.z, w2)
        LSTEP(v0.w, v1.w, w3)
#undef LSTEP
    }
    float d0 = dinv[r0], d1 = dinv[r0 + 1];
    a00 *= d0; a01 *= d0; a02 *= d0; a03 *= d0;
    a10 *= d1; a11 *= d1; a12 *= d1; a13 *= d1;
    int q0 = __builtin_amdgcn_cvt_pk_fp8_f32(a00, a01, 0, false);
    q0 = __builtin_amdgcn_cvt_pk_fp8_f32(a02, a03, q0, true);
    int q1 = __builtin_amdgcn_cvt_pk_fp8_f32(a10, a11, 0, false);
    q1 = __builtin_amdgcn_cvt_pk_fp8_f32(a12, a13, q1, true);
    tmp8[r0 * 8 + kg] = (unsigned int)q0;
    tmp8[(r0 + 1) * 8 + kg] = (unsigned int)q1;
}

// shared gather loop: one wave per dest node, 8 edge slots x 8 feat-quads,
// burst of 4 prefetched srn4 loads + 4 gathers. Returns per-lane partial
// accumulators reduced across slots (lanes g==0 hold the 4-feat result).
#define AGG_BODY \
    int lane = threadIdx.x & 63; \
    int g = lane >> 3; \
    int q = lane & 7; \
    int end = rowptr[wid]; \
    int start = (wid == 0) ? 0 : rowptr[wid - 1]; \
    float a0 = 0, a1 = 0, a2 = 0, a3 = 0; \
    float b0 = 0, b1 = 0, b2 = 0, b3 = 0; \
    int e = start + g; \
    for (; e + 24 < end; e += 32) { \
        unsigned int p0 = srn4[e]; \
        unsigned int p1 = srn4[e + 8]; \
        unsigned int p2 = srn4[e + 16]; \
        unsigned int p3 = srn4[e + 24]; \
        unsigned int u0 = tmp8[(size_t)(p0 & SRCMASK) * 8 + q]; \
        unsigned int u1 = tmp8[(size_t)(p1 & SRCMASK) * 8 + q]; \
        unsigned int u2 = tmp8[(size_t)(p2 & SRCMASK) * 8 + q]; \
        unsigned int u3 = tmp8[(size_t)(p3 & SRCMASK) * 8 + q]; \
        float w0 = __uint_as_float((p0 >> 1) & 0x7FFF0000u); \
        float w1 = __uint_as_float((p1 >> 1) & 0x7FFF0000u); \
        float w2 = __uint_as_float((p2 >> 1) & 0x7FFF0000u); \
        float w3 = __uint_as_float((p3 >> 1) & 0x7FFF0000u); \
        floatx2 lo, hi; \
        lo = __builtin_amdgcn_cvt_pk_f32_fp8(u0, false); \
        hi = __builtin_amdgcn_cvt_pk_f32_fp8(u0, true); \
        a0 = fmaf(w0, lo.x, a0); a1 = fmaf(w0, lo.y, a1); \
        a2 = fmaf(w0, hi.x, a2); a3 = fmaf(w0, hi.y, a3); \
        lo = __builtin_amdgcn_cvt_pk_f32_fp8(u1, false); \
        hi = __builtin_amdgcn_cvt_pk_f32_fp8(u1, true); \
        b0 = fmaf(w1, lo.x, b0); b1 = fmaf(w1, lo.y, b1); \
        b2 = fmaf(w1, hi.x, b2); b3 = fmaf(w1, hi.y, b3); \
        lo = __builtin_amdgcn_cvt_pk_f32_fp8(u2, false); \
        hi = __builtin_amdgcn_cvt_pk_f32_fp8(u2, true); \
        a0 = fmaf(w2, lo.x, a0); a1 = fmaf(w2, lo.y, a1); \
        a2 = fmaf(w2, hi.x, a2); a3 = fmaf(w2, hi.y, a3); \
        lo = __builtin_amdgcn_cvt_pk_f32_fp8(u3, false); \
        hi = __builtin_amdgcn_cvt_pk_f32_fp8(u3, true); \
        b0 = fmaf(w3, lo.x, b0); b1 = fmaf(w3, lo.y, b1); \
        b2 = fmaf(w3, hi.x, b2); b3 = fmaf(w3, hi.y, b3); \
    } \
    for (; e < end; e += 8) { \
        unsigned int p = srn4[e]; \
        unsigned int u = tmp8[(size_t)(p & SRCMASK) * 8 + q]; \
        float w = __uint_as_float((p >> 1) & 0x7FFF0000u); \
        floatx2 lo = __builtin_amdgcn_cvt_pk_f32_fp8(u, false); \
        floatx2 hi = __builtin_amdgcn_cvt_pk_f32_fp8(u, true); \
        a0 = fmaf(w, lo.x, a0); a1 = fmaf(w, lo.y, a1); \
        a2 = fmaf(w, hi.x, a2); a3 = fmaf(w, hi.y, a3); \
    } \
    a0 += b0; a1 += b1; a2 += b2; a3 += b3; \
    a0 += __shfl_xor(a0, 8, 64); a1 += __shfl_xor(a1, 8, 64); \
    a2 += __shfl_xor(a2, 8, 64); a3 += __shfl_xor(a3, 8, 64); \
    a0 += __shfl_xor(a0, 16, 64); a1 += __shfl_xor(a1, 16, 64); \
    a2 += __shfl_xor(a2, 16, 64); a3 += __shfl_xor(a3, 16, 64); \
    a0 += __shfl_xor(a0, 32, 64); a1 += __shfl_xor(a1, 32, 64); \
    a2 += __shfl_xor(a2, 32, 64); a3 += __shfl_xor(a3, 32, 64);

// plain aggregate (layer 3): writes fp32 h for pooling (no relu).
__global__ void aggregate(const unsigned int* __restrict__ srn4,
                          const int* __restrict__ rowptr,
                          const float* __restrict__ dinv,
                          const float* __restrict__ bias,
                          const unsigned int* __restrict__ tmp8,
                          float* __restrict__ h) {
    int wid = (blockIdx.x * 256 + threadIdx.x) >> 6;
    if (wid >= NN) return;
    AGG_BODY
    if (g == 0) {
        float d = dinv[wid];
        unsigned int sv = tmp8[(size_t)wid * 8 + q];
        floatx2 slo = __builtin_amdgcn_cvt_pk_f32_fp8(sv, false);
        floatx2 shi = __builtin_amdgcn_cvt_pk_f32_fp8(sv, true);
        float4 bq = ((const float4*)bias)[q];
        float4 o;
        o.x = bq.x + d * (slo.x + a0);
        o.y = bq.y + d * (slo.y + a1);
        o.z = bq.z + d * (shi.x + a2);
        o.w = bq.w + d * (shi.y + a3);
        ((float4*)(h + (size_t)wid * HID))[q] = o;
    }
}

// fused aggregate + relu + 32x32 next-layer linear + fp8 store (layers 1->2,
// 2->3). The wave holds the full h row; stage it via 512B LDS (same-wave
// program order, no barrier), matvec with W from global (L1-hot, coalesced),
// write tmp8_out = fp8(dinv * (relu(h) @ Wn)).
__global__ void agg_lin(const unsigned int* __restrict__ srn4,
                        const int* __restrict__ rowptr,
                        const float* __restrict__ dinv,
                        const float* __restrict__ bias,
                        const float* __restrict__ Wn,
                        const unsigned int* __restrict__ tmp8,
                        unsigned int* __restrict__ tmp8_out) {
    __shared__ float hrow[4][HID];
    int wid = (blockIdx.x * 256 + threadIdx.x) >> 6;
    if (wid >= NN) return;
    int wv = threadIdx.x >> 6;   // wave in block 0..3
    AGG_BODY
    float d = dinv[wid];
    if (g == 0) {
        unsigned int sv = tmp8[(size_t)wid * 8 + q];
        floatx2 slo = __builtin_amdgcn_cvt_pk_f32_fp8(sv, false);
        floatx2 shi = __builtin_amdgcn_cvt_pk_f32_fp8(sv, true);
        float4 bq = ((const float4*)bias)[q];
        float4 o;
        o.x = fmaxf(bq.x + d * (slo.x + a0), 0.f);
        o.y = fmaxf(bq.y + d * (slo.y + a1), 0.f);
        o.z = fmaxf(bq.z + d * (shi.x + a2), 0.f);
        o.w = fmaxf(bq.w + d * (shi.y + a3), 0.f);
        *((float4*)&hrow[wv][4 * q]) = o;
    }
    // in-wave 32x32 matvec: 64 lanes = 32 outputs x 2 k-halves
    int j = lane & 31, half = lane >> 5;
    const float* hr = hrow[wv];
    const float* wc = Wn + j;
    float y = 0.f;
#pragma unroll
    for (int k = 0; k < 16; ++k) {
        int kk = half * 16 + k;
        y = fmaf(hr[kk], wc[kk * 32], y);
    }
    y += __shfl_xor(y, 32, 64);
    y *= d;
    float y1 = __shfl_down(y, 1, 64);
    float y2 = __shfl_down(y, 2, 64);
    float y3 = __shfl_down(y, 3, 64);
    if (half == 0 && (j & 3) == 0) {
        int w0 = __builtin_amdgcn_cvt_pk_fp8_f32(y, y1, 0, false);
        w0 = __builtin_amdgcn_cvt_pk_fp8_f32(y2, y3, w0, true);
        tmp8_out[wid * 8 + (j >> 2)] = (unsigned int)w0;
    }
}

// sorted-batch run-length pooling (3125 chunks x 32 nodes, boundary atomics)
__global__ void pool_k(const float* __restrict__ h, const int* __restrict__ batch,
                       float* __restrict__ sums, float* __restrict__ counts) {
    int t = blockIdx.x * 256 + threadIdx.x;
    int chunk = t >> 5, k = t & 31;
    int n0 = chunk * 32;
    if (n0 >= NN) return;
    int n1 = min(n0 + 32, NN);
    int g = batch[n0];
    float acc = 0.f, cacc = 0.f;
    for (int i = n0; i < n1; ++i) {
        int gi = batch[i];
        if (gi != g) {
            atomicAdd(&sums[g * HID + k], acc);
            if (k == 0) atomicAdd(&counts[g], cacc);
            g = gi; acc = 0.f; cacc = 0.f;
        }
        acc += h[(size_t)i * HID + k];
        cacc += 1.f;
    }
    atomicAdd(&sums[g * HID + k], acc);
    if (k == 0) atomicAdd(&counts[g], cacc);
}

// MLP: one block per graph, one wave; thread k owns output column k.
__global__ __launch_bounds__(64)
void mlp_k(const float* __restrict__ sums, const float* __restrict__ counts,
           const float* __restrict__ Wm0, const float* __restrict__ bm0,
           const float* __restrict__ Wm1, const float* __restrict__ bm1,
           const float* __restrict__ Wout, const float* __restrict__ bout,
           float* __restrict__ out) {
    __shared__ float g0[HID];
    __shared__ float g1[MH];
    __shared__ float g2[MH];
    int g = blockIdx.x;
    int k = threadIdx.x;
    if (k < HID) g0[k] = sums[g * HID + k] / fmaxf(counts[g], 1.0f);
    __syncthreads();
    float acc = bm0[k];
#pragma unroll
    for (int j = 0; j < HID; ++j) acc = fmaf(g0[j], Wm0[j * MH + k], acc);
    g1[k] = fmaxf(acc, 0.f);
    __syncthreads();
    float acc2 = bm1[k];
#pragma unroll
    for (int j = 0; j < MH; ++j) acc2 = fmaf(g1[j], Wm1[j * MH + k], acc2);
    g2[k] = fmaxf(acc2, 0.f);
    __syncthreads();
    if (k < NC) {
        float acc3 = bout[k];
#pragma unroll
        for (int j = 0; j < MH; ++j) acc3 = fmaf(g2[j], Wout[j * NC + k], acc3);
        out[g * NC + k] = acc3;
    }
}

extern "C" void kernel_launch(void* const* d_in, const int* in_sizes, int n_in,
                              void* d_out, int out_size, void* d_ws, size_t ws_size,
                              hipStream_t stream) {
    const float* x    = (const float*)d_in[0];
    const int*   ei   = (const int*)d_in[1];
    const float* ew   = (const float*)d_in[2];
    const int*   batch= (const int*)d_in[3];
    const float* W1   = (const float*)d_in[4];
    const float* b1   = (const float*)d_in[5];
    const float* W2   = (const float*)d_in[6];
    const float* b2   = (const float*)d_in[7];
    const float* W3   = (const float*)d_in[8];
    const float* b3   = (const float*)d_in[9];
    const float* Wm0  = (const float*)d_in[10];
    const float* bm0  = (const float*)d_in[11];
    const float* Wm1  = (const float*)d_in[12];
    const float* bm1  = (const float*)d_in[13];
    const float* Wout = (const float*)d_in[14];
    const float* bout = (const float*)d_in[15];
    float* out = (float*)d_out;

    // workspace: srn4 | S (tre+cnt2+scanned <-> tmp8+tmp8b+hA) | small bufs
    char* p = (char*)d_ws;
    unsigned int* srn4 = (unsigned int*)p; p += sizeof(unsigned int) * (size_t)NE; // 12.8 MB
    char*  S   = p;                      p += 12 * (size_t)NE;                // 38.4 MB shared
    int2*  tre = (int2*)S;                                                    // 25.6 MB
    int*   cnt2    = (int*)(S + sizeof(int2) * (size_t)NE);                   // 1.6 MB (dies pre-layer1)
    int*   scanned = cnt2 + SCANL;                                            // 1.6 MB
    unsigned int* tmp8  = (unsigned int*)S;                                   // 3.2 MB
    unsigned int* tmp8b = tmp8 + (size_t)NN * 8;                              // 3.2 MB
    float* hA  = (float*)(S + 2 * (size_t)NN * HID);                          // 12.8 MB
    int*   bsum    = (int*)p;            p += sizeof(int) * 512;
    float* dinv    = (float*)p;          p += sizeof(float) * NN;
    int*   rowptr  = (int*)p;            p += sizeof(int) * NN;
    float* sums    = (float*)p;          p += sizeof(float) * NG * HID;
    float* counts  = (float*)p;

    dim3 blk(256);
    const int NB_SCAN = (SCANL + 1023) / 1024;  // 391
    const int NB_LIN = (NN + 63) / 64;          // 1563

    hist_bkt<<<NBLK, 1024, 0, stream>>>(ei, cnt2);
    scan_block<<<NB_SCAN, blk, 0, stream>>>(cnt2, scanned, bsum, SCANL);
    scan_top<<<1, 64, 0, stream>>>(bsum, NB_SCAN, sums);  // also zeroes sums+counts
    scan_add<<<(SCANL + 255) / 256, blk, 0, stream>>>(scanned, bsum, SCANL);
    scatter_bkt<<<NBLK, 1024, 0, stream>>>(ei, ew, cnt2, scanned, tre);
    sort_k<<<NBKT, 512, 0, stream>>>(tre, scanned, srn4, rowptr, dinv);

    // layer 1 linear, then fused agg1+linear2, fused agg2+linear3, plain agg3
    linear_k<FIN, false><<<NB_LIN, blk, 0, stream>>>(x, W1, dinv, tmp8);
    agg_lin<<<25000, blk, 0, stream>>>(srn4, rowptr, dinv, b1, W2, tmp8, tmp8b);
    agg_lin<<<25000, blk, 0, stream>>>(srn4, rowptr, dinv, b2, W3, tmp8b, tmp8);
    aggregate<<<25000, blk, 0, stream>>>(srn4, rowptr, dinv, b3, tmp8, hA);

    pool_k<<<391, blk, 0, stream>>>(hA, batch, sums, counts);
    mlp_k<<<NG, 64, 0, stream>>>(sums, counts, Wm0, bm0, Wm1, bm1, Wout, bout, out);
}